// Round 9
// baseline (237.221 us; speedup 1.0000x reference)
//
#include <hip/hip_runtime.h>

#define HW (512 * 512)          // elements per (batch, channel) row
#define BATCH 64
#define NROWS (BATCH * 3)       // 192
#define NB 100
#define NCOPY 16                // LDS sub-histogram copies
#define CSTRIDE 101             // copy stride -> 16 distinct banks across copies
#define HIST_CHUNKS 16          // hist units per row (64 KB each)
#define NORM_CHUNKS 32          // norm units per row (32 KB each)
#define HUNITS (NROWS * HIST_CHUNKS)   // 3072
#define NUNITS (NROWS * NORM_CHUNKS)   // 6144
#define GRID 1024               // 4 blocks/CU -> all co-resident (deadlock-free spins)
#define TPB 256
#define HPB (HUNITS / GRID)     // 3 hist units per block
#define NPB (NUNITS / GRID)     // 6 norm units per block (same 192KB range as its hist units)

typedef float f32x4 __attribute__((ext_vector_type(4)));

__global__ __launch_bounds__(TPB, 4) void fused_kernel(
    const float* __restrict__ lab,
    const float* __restrict__ ref_l,
    const float* __restrict__ ref_a,
    const float* __restrict__ ref_b,
    float* __restrict__ out,
    unsigned int* __restrict__ part,   // HUNITS*NB u32
    unsigned int* __restrict__ cnt)    // NROWS u32, zeroed each call
{
    __shared__ unsigned int sh[NCOPY * CSTRIDE];   // hist copies; reused as hh+so later

    // ---------------- Phase 1: hist units (no waits -> always completes) ----------------
    const int hn4 = HW / 4 / HIST_CHUNKS;          // 4096 float4 per hist unit
    for (int j = 0; j < HPB; ++j) {
        const int u = blockIdx.x * HPB + j;
        const int row = u / HIST_CHUNKS, chunk = u % HIST_CHUNKS, c = row % 3;
        const float lo = (c == 0) ? 0.0f   : -128.0f;
        const float hi = (c == 0) ? 100.0f : 127.0f;
        const float bs = (c == 0) ? 1.0f   : 2.55f;

        for (int i = threadIdx.x; i < NCOPY * CSTRIDE; i += TPB) sh[i] = 0;
        __syncthreads();

        unsigned int* wh = &sh[(threadIdx.x & (NCOPY - 1)) * CSTRIDE];
        const f32x4* p = (const f32x4*)(lab + (size_t)row * HW) + (size_t)chunk * hn4;
        for (int i = threadIdx.x; i < hn4; i += TPB) {
            f32x4 v = p[i];
#pragma unroll
            for (int k = 0; k < 4; ++k) {
                float x = v[k];
                if (x >= lo && x <= hi) {                   // histc: outside range ignored
                    int idx = (int)floorf((x - lo) / bs);   // f32 true division (bit-exact)
                    idx = idx > (NB - 1) ? (NB - 1) : idx;  // x == hi -> last bin
                    atomicAdd(&wh[idx], 1u);
                }
            }
        }
        __syncthreads();
        for (int i = threadIdx.x; i < NB; i += TPB) {
            unsigned int s = 0;
#pragma unroll
            for (int jj = 0; jj < NCOPY; ++jj) s += sh[jj * CSTRIDE + i];
            part[(size_t)u * NB + i] = s;
        }
        __syncthreads();                                     // all partial stores issued
        if (threadIdx.x == 0) {
            __threadfence();                                 // release: partials visible device-wide
            atomicAdd(&cnt[row], 1u);
        }
        __syncthreads();                                     // sh safe to re-zero next iter
    }

    // ---------------- Phase 2: norm units over the SAME byte range (L2/L3-hot) ----------------
    unsigned int* hh = sh;            // NB sums
    float* so = (float*)&sh[NB];      // scale, offset
    const int nn4 = HW / 4 / NORM_CHUNKS;          // 2048 float4 per norm unit
    for (int j = 0; j < NPB; ++j) {
        const int u = blockIdx.x * NPB + j;
        const int row = u / NORM_CHUNKS, chunk = u % NORM_CHUNKS, c = row % 3;

        if (threadIdx.x == 0) {      // wait until this row's 16 hist chunks are published
            while (__hip_atomic_load(&cnt[row], __ATOMIC_ACQUIRE,
                                     __HIP_MEMORY_SCOPE_AGENT) < HIST_CHUNKS)
                __builtin_amdgcn_s_sleep(2);
        }
        __syncthreads();

        if (threadIdx.x < NB) {
            unsigned int s = 0;
            const unsigned int* p = part + (size_t)row * HIST_CHUNKS * NB + threadIdx.x;
#pragma unroll
            for (int k = 0; k < HIST_CHUNKS; ++k) s += p[(size_t)k * NB];
            hh[threadIdx.x] = s;
        }
        __syncthreads();

        if (threadIdx.x == 0) {
            if (c == 0) {
                // L: second-highest bin (jax top_k tie-break: lower index first).
                long best = -1, sec = -1; int bi = 0, si = 0;
                for (int i = 0; i < NB; ++i) {
                    long v = (long)hh[i];
                    if (v > best)     { sec = best; si = bi; best = v; bi = i; }
                    else if (v > sec) { sec = v;  si = i; }
                }
                float pL = (si + 0.5f);
                so[0] = ref_l[0] / pL * (1.0f / 200.0f);
                so[1] = 0.5f;
            } else {
                long best = -1; int bi = 0;
                for (int i = 0; i < NB; ++i) {
                    long v = (long)hh[i];
                    if (v > best) { best = v; bi = i; }
                }
                float p = -128.0f + (bi + 0.5f) * 2.55f;
                float r = (c == 1) ? ref_a[0] : ref_b[0];
                so[0] = r / p * (1.0f / 255.0f);
                so[1] = 128.0f / 255.0f;
            }
        }
        __syncthreads();

        const float s = so[0];
        const float o = so[1];
        const size_t base = (size_t)row * (HW / 4) + (size_t)chunk * nn4;
        const f32x4* ip = (const f32x4*)lab + base;
        f32x4*       op = (f32x4*)out + base;
        for (int i = threadIdx.x; i < nn4; i += TPB) {
            f32x4 v = ip[i];                               // plain load: cache-served (R8 A/B)
            v.x = fmaf(v.x, s, o);
            v.y = fmaf(v.y, s, o);
            v.z = fmaf(v.z, s, o);
            v.w = fmaf(v.w, s, o);
            __builtin_nontemporal_store(v, &op[i]);        // nt store: proven +9 us (R3 vs R5)
        }
        __syncthreads();                                   // hh/so safe for next unit
    }
}

extern "C" void kernel_launch(void* const* d_in, const int* in_sizes, int n_in,
                              void* d_out, int out_size, void* d_ws, size_t ws_size,
                              hipStream_t stream) {
    const float* lab   = (const float*)d_in[0];
    const float* ref_l = (const float*)d_in[1];
    const float* ref_a = (const float*)d_in[2];
    const float* ref_b = (const float*)d_in[3];
    float* out = (float*)d_out;

    unsigned int* part = (unsigned int*)d_ws;      // 3072*100 u32 = 1.23 MB
    unsigned int* cnt  = (unsigned int*)((char*)d_ws + (size_t)HUNITS * NB * sizeof(unsigned int));

    (void)hipMemsetAsync(cnt, 0, NROWS * sizeof(unsigned int), stream);
    hipLaunchKernelGGL(fused_kernel, dim3(GRID), dim3(TPB), 0, stream,
                       lab, ref_l, ref_a, ref_b, out, part, cnt);
}

// Round 10
// 100.574 us; speedup vs baseline: 2.3587x; 2.3587x over previous
//
#include <hip/hip_runtime.h>

#define HW (512 * 512)          // elements per (batch, channel) row
#define BATCH 64
#define NROWS (BATCH * 3)       // 192
#define NB 100
#define NCOPY 32                // LDS sub-histogram copies (2 lanes/copy -> min atomic clash)
#define CSTRIDE 101             // copy stride: bank(101c)=5c mod 32, gcd(5,32)=1 -> all distinct
#define HIST_CHUNKS 8           // 1536 hist blocks -> single co-resident round
#define NORM_CHUNKS 32          // blocks per row in normalize pass

typedef float f32x4 __attribute__((ext_vector_type(4)));

// ---------------- Pass 1: per-(row,chunk) partial 100-bin histogram ----------------
__global__ __launch_bounds__(256) void hist_kernel(const float* __restrict__ lab,
                                                   unsigned int* __restrict__ part) {
    __shared__ unsigned int sh[NCOPY * CSTRIDE];   // 12.9 KB
    for (int i = threadIdx.x; i < NCOPY * CSTRIDE; i += 256) sh[i] = 0;
    __syncthreads();

    const int row   = blockIdx.x / HIST_CHUNKS;   // b*3 + c
    const int chunk = blockIdx.x % HIST_CHUNKS;
    const int c     = row % 3;

    // histc parameters (match reference float32 math exactly)
    const float lo = (c == 0) ? 0.0f   : -128.0f;
    const float hi = (c == 0) ? 100.0f : 127.0f;
    const float bs = (c == 0) ? 1.0f   : 2.55f;

    unsigned int* wh = &sh[(threadIdx.x & (NCOPY - 1)) * CSTRIDE];

    const int n4 = HW / 4 / HIST_CHUNKS;          // 8192 float4 per block
    const f32x4* p = (const f32x4*)(lab + (size_t)row * HW) + (size_t)chunk * n4;

    for (int i = threadIdx.x; i < n4; i += 256) {
        f32x4 v = p[i];
#pragma unroll
        for (int k = 0; k < 4; ++k) {
            float x = v[k];
            if (x >= lo && x <= hi) {                   // histc: outside range ignored
                int idx = (int)floorf((x - lo) / bs);   // f32 true division (bit-exact vs ref)
                idx = idx > (NB - 1) ? (NB - 1) : idx;  // x == hi -> last bin
                atomicAdd(&wh[idx], 1u);
            }
        }
    }
    __syncthreads();

    for (int i = threadIdx.x; i < NB; i += 256) {
        unsigned int s = 0;
#pragma unroll
        for (int j = 0; j < NCOPY; ++j) s += sh[j * CSTRIDE + i];
        part[((size_t)row * HIST_CHUNKS + chunk) * NB + i] = s;   // plain store, no memset
    }
}

// ---------------- Pass 2: fused peaks + affine normalize ----------------
// Each block re-derives its OWN row's (scale, offset) from the partials
// (3.2 KB L2-resident reads + ~100-iter scan), then streams its chunk.
// L rows: second peak (jax top_k tie-break: lower index first).
// A/B rows: argmax (first occurrence).
__global__ __launch_bounds__(256) void norm_kernel(const float* __restrict__ lab,
                                                   const unsigned int* __restrict__ part,
                                                   const float* __restrict__ ref_l,
                                                   const float* __restrict__ ref_a,
                                                   const float* __restrict__ ref_b,
                                                   float* __restrict__ out) {
    __shared__ unsigned int hh[NB];
    __shared__ float so[2];

    const int row   = blockIdx.x / NORM_CHUNKS;   // b*3 + c
    const int chunk = blockIdx.x % NORM_CHUNKS;
    const int c     = row % 3;

    // Reduce this row's partial histograms (coalesced across bins).
    if (threadIdx.x < NB) {
        unsigned int s = 0;
        const unsigned int* p = part + (size_t)row * HIST_CHUNKS * NB + threadIdx.x;
#pragma unroll
        for (int k = 0; k < HIST_CHUNKS; ++k) s += p[(size_t)k * NB];
        hh[threadIdx.x] = s;
    }
    __syncthreads();

    if (threadIdx.x == 0) {
        if (c == 0) {
            // L: second-highest bin.
            long best = -1, sec = -1; int bi = 0, si = 0;
            for (int i = 0; i < NB; ++i) {
                long cnt = (long)hh[i];
                if (cnt > best)     { sec = best; si = bi; best = cnt; bi = i; }
                else if (cnt > sec) { sec = cnt;  si = i; }
            }
            float pL = (si + 0.5f);                  // lo = 0, bin = 1
            so[0] = ref_l[0] / pL * (1.0f / 200.0f);
            so[1] = 0.5f;
        } else {
            long best = -1; int bi = 0;
            for (int i = 0; i < NB; ++i) {
                long cnt = (long)hh[i];
                if (cnt > best) { best = cnt; bi = i; }
            }
            float p = -128.0f + (bi + 0.5f) * 2.55f;
            float r = (c == 1) ? ref_a[0] : ref_b[0];
            so[0] = r / p * (1.0f / 255.0f);
            so[1] = 128.0f / 255.0f;
        }
    }
    __syncthreads();

    const float s = so[0];
    const float o = so[1];

    const int n4 = HW / 4 / NORM_CHUNKS;           // 2048
    const size_t base = (size_t)row * (HW / 4) + (size_t)chunk * n4;
    const f32x4* ip = (const f32x4*)lab + base;
    f32x4*       op = (f32x4*)out + base;

    for (int i = threadIdx.x; i < n4; i += 256) {
        f32x4 v = ip[i];                            // plain load: cache-served (R8 A/B)
        v.x = fmaf(v.x, s, o);
        v.y = fmaf(v.y, s, o);
        v.z = fmaf(v.z, s, o);
        v.w = fmaf(v.w, s, o);
        __builtin_nontemporal_store(v, &op[i]);     // nt store: proven +9 us (R3 vs R5)
    }
}

extern "C" void kernel_launch(void* const* d_in, const int* in_sizes, int n_in,
                              void* d_out, int out_size, void* d_ws, size_t ws_size,
                              hipStream_t stream) {
    const float* lab   = (const float*)d_in[0];
    const float* ref_l = (const float*)d_in[1];
    const float* ref_a = (const float*)d_in[2];
    const float* ref_b = (const float*)d_in[3];
    float* out = (float*)d_out;

    unsigned int* part = (unsigned int*)d_ws;      // NROWS*HIST_CHUNKS*NB u32 = 614 KB

    hipLaunchKernelGGL(hist_kernel, dim3(NROWS * HIST_CHUNKS), dim3(256), 0, stream,
                       lab, part);
    hipLaunchKernelGGL(norm_kernel, dim3(NROWS * NORM_CHUNKS), dim3(256), 0, stream,
                       lab, part, ref_l, ref_a, ref_b, out);
}